// Round 9
// baseline (12286.940 us; speedup 1.0000x reference)
//
#include <hip/hip_runtime.h>
#include <stdint.h>
#include <math.h>

#define NS 8192
#define NSTEPS 200
#define DBc 128
#define NBLK 32
#define TPB 256

typedef unsigned int u32;
typedef unsigned short u16;

// ws float-offset layout (float slots) — identical to round 6 (passing)
#define WS_BARC   0
#define WS_BARG   32
#define WS_KEYINIT 64
#define WS_KFIN   66
#define WS_KC     128
#define WS_KST    640
#define WS_PM1    2048     // [2][128] per-wave max (S1)
#define WS_PE1    2304     // [2][128] per-wave sumexp (S1)
#define WS_PM2    2560     // [2][128] (S2)
#define WS_PE2    2816     // [2][128] (S2)
#define WS_S1     4096     // [2][8192]
#define WS_S2     20480    // [2][8192]
#define WS_LL     36864    // [2][8192]
#define WS_LWF    WS_S2    // final log-weights alias S2 parity0 (dead then)
#define WS_ANC_F  53248    // u16[199*8192] = 815104 floats -> ends 868352
#define WS_TRACE  868352   // float[200*8192*8]

#define SW(x) ((x)+((x)>>5))   // LDS swizzle for CUM (injective, conflict-free rows)

// ======================= threefry2x32-20 =======================
__device__ __forceinline__ u32 rotl32(u32 v, int r){ return (v<<r)|(v>>(32-r)); }

__device__ __forceinline__ void tf2x32(u32 k0,u32 k1,u32 c0,u32 c1,u32&o0,u32&o1){
  u32 ks2 = k0^k1^0x1BD11BDAu;
  u32 x0=c0+k0, x1=c1+k1;
#define TFR(R) { x0+=x1; x1=rotl32(x1,(R)); x1^=x0; }
  TFR(13) TFR(15) TFR(26) TFR(6)
  x0+=k1;  x1+=ks2+1u;
  TFR(17) TFR(29) TFR(16) TFR(24)
  x0+=ks2; x1+=k0+2u;
  TFR(13) TFR(15) TFR(26) TFR(6)
  x0+=k0;  x1+=k1+3u;
  TFR(17) TFR(29) TFR(16) TFR(24)
  x0+=k1;  x1+=ks2+4u;
  TFR(13) TFR(15) TFR(26) TFR(6)
  x0+=ks2; x1+=k0+5u;
#undef TFR
  o0=x0; o1=x1;
}

__device__ __forceinline__ u32 jax_bits_elem(u32 k0,u32 k1,u32 i){
  u32 a,b; tf2x32(k0,k1,0u,i,a,b); return a^b;
}

__device__ __forceinline__ float bits_to_f01(u32 bits){
  return __uint_as_float((bits>>9)|0x3f800000u) - 1.0f;
}

__device__ __forceinline__ float log1pf_acc(float a){
#pragma clang fp contract(off)
  float u = 1.0f + a;
  if (u == 1.0f) return a;
  float l = logf(u);
  return l * (a / (u - 1.0f));
}

__device__ __forceinline__ float erfinv_xla(float x){
#pragma clang fp contract(off)
  float a = -(x*x);
  float w = -log1pf_acc(a);
  float p;
  if (w < 5.0f){
    w = w - 2.5f;
    p = 2.81022636e-08f;
    p = 3.43273939e-07f + p*w;
    p = -3.5233877e-06f + p*w;
    p = -4.39150654e-06f + p*w;
    p = 0.00021858087f  + p*w;
    p = -0.00125372503f + p*w;
    p = -0.00417768164f + p*w;
    p = 0.246640727f    + p*w;
    p = 1.50140941f     + p*w;
  } else {
    w = sqrtf(w) - 3.0f;
    p = -0.000200214257f;
    p = 0.000100950558f + p*w;
    p = 0.00134934322f  + p*w;
    p = -0.00367342844f + p*w;
    p = 0.00573950773f  + p*w;
    p = -0.0076224613f  + p*w;
    p = 0.00943887047f  + p*w;
    p = 1.00167406f     + p*w;
    p = 2.83297682f     + p*w;
  }
  return p*x;
}

__device__ __forceinline__ float jax_normal_elem(u32 k0,u32 k1,u32 i){
#pragma clang fp contract(off)
  float f = bits_to_f01(jax_bits_elem(k0,k1,i));
  float u = f*2.0f + (-0.99999994039535522f);
  u = fmaxf(-0.99999994039535522f, u);
  return 1.41421356237309515f * erfinv_xla(u);
}

__device__ __forceinline__ float jax_uniform01_scalar(u32 k0,u32 k1){
  return bits_to_f01(jax_bits_elem(k0,k1,0u));
}

// ======================= agent-scope access (cross-XCD coherent) =======================
__device__ __forceinline__ float aload(const float* p){
  return __hip_atomic_load(p, __ATOMIC_RELAXED, __HIP_MEMORY_SCOPE_AGENT);
}
__device__ __forceinline__ void astore(float* p, float v){
  __hip_atomic_store(p, v, __ATOMIC_RELAXED, __HIP_MEMORY_SCOPE_AGENT);
}

// fused sense-reversal grid barrier — round 6 verbatim (validated)
__device__ __forceinline__ void gridbar(u32* cnt, u32* gen, u32& g){
  __syncthreads();
  g++;
  if(threadIdx.x==0){
    u32 old=__hip_atomic_fetch_add(cnt,1u,__ATOMIC_ACQ_REL,__HIP_MEMORY_SCOPE_AGENT);
    if(old==(u32)(NBLK-1)){
      __hip_atomic_store(cnt,0u,__ATOMIC_RELAXED,__HIP_MEMORY_SCOPE_AGENT);
      __hip_atomic_store(gen,g,__ATOMIC_RELEASE,__HIP_MEMORY_SCOPE_AGENT);
    } else {
      u32 cur;
      do {
        __builtin_amdgcn_s_sleep(4);
        cur=__hip_atomic_load(gen,__ATOMIC_RELAXED,__HIP_MEMORY_SCOPE_AGENT);
      } while(cur<g);
      (void)__hip_atomic_load(gen,__ATOMIC_ACQUIRE,__HIP_MEMORY_SCOPE_AGENT);
    }
  }
  __syncthreads();
}

// ======================= wave helpers (round 6 verbatim) =======================
__device__ __forceinline__ float wave_max(float v){
  #pragma unroll
  for(int m=1;m<64;m<<=1) v=fmaxf(v,__shfl_xor(v,m,64));
  return v;
}
__device__ __forceinline__ float wave_sum(float v){
  #pragma unroll
  for(int m=1;m<64;m<<=1) v+=__shfl_xor(v,m,64);
  return v;
}
__device__ __forceinline__ float wave_incl_scan(float v,int lane){
  #pragma unroll
  for(int o=1;o<64;o<<=1){ float u=__shfl_up(v,o,64); if(lane>=o) v+=u; }
  return v;
}

__device__ __forceinline__ int bsearch8192(const float* c,float v){
  int lo=0,hi=NS;
  while(lo<hi){ int mid=(lo+hi)>>1; if(c[mid]<v) lo=mid+1; else hi=mid; }
  return lo>NS-1?NS-1:lo;
}

__device__ void chol8(const float* A,float* L){
  for(int c=0;c<8;c++){
    for(int r=c;r<8;r++){
      float s=A[r*8+c];
      for(int k=0;k<c;k++) s-=L[r*(r+1)/2+k]*L[c*(c+1)/2+k];
      L[r*(r+1)/2+c]=(r==c)? sqrtf(s) : s/L[c*(c+1)/2+c];
    }
  }
}

// r6-exact two-stage search: wave-select on EX (exclusive prefixes), then
// first-j-with-CUM>=tau binary search on the materialized serial cumsum.
// CUM is non-decreasing (adds of exp>=0), so binsearch == r6's serial
// "first c>=tau" scan, with r6's exact fallback.
__device__ __forceinline__ int search_r6(const float* EX, const float* CUM, float tau){
  int lo=0,hi=127;
  while(lo<hi){ int mid=(lo+hi+1)>>1; if(EX[mid]<=tau) lo=mid; else hi=mid-1; }
  int wt=lo;
  int base=wt<<6;
  int lo2=0,hi2=64;
  while(lo2<hi2){ int mid=(lo2+hi2)>>1; if(CUM[SW(base+mid)]<tau) lo2=mid+1; else hi2=mid; }
  if(lo2<64) return base+lo2;
  int nx=base+64; return (nx>NS-1)?NS-1:nx;
}

// ======================= k_pre: barrier init + key chain (round 6 verbatim) =======================
__global__ __launch_bounds__(256) void k_pre(const int* __restrict__ seedp, float* wsf){
  u32* BARC=(u32*)(wsf+WS_BARC); u32* BARG=(u32*)(wsf+WS_BARG);
  u32* KI=(u32*)(wsf+WS_KEYINIT); u32* KF=(u32*)(wsf+WS_KFIN);
  u32* KC=(u32*)(wsf+WS_KC); u32* KST=(u32*)(wsf+WS_KST);
  int tid=threadIdx.x;
  if(tid==0){
    BARC[0]=0u; BARG[0]=0u;
    u32 s=(u32)seedp[0];
    u32 a,b;
    tf2x32(0u,s,0u,0u,a,b); KC[0]=a; KC[1]=b;
    tf2x32(0u,s,0u,1u,a,b); KI[0]=a; KI[1]=b;
    for(int t=1;t<NSTEPS;t++){
      tf2x32(KC[2*(t-1)],KC[2*(t-1)+1],0u,0u,a,b);
      KC[2*t]=a; KC[2*t+1]=b;
    }
    KF[0]=KC[2*(NSTEPS-1)]; KF[1]=KC[2*(NSTEPS-1)+1];
  }
  __syncthreads();
  int t=tid;
  if(t>=1 && t<NSTEPS){
    u32 k0=KC[2*(t-1)], k1=KC[2*(t-1)+1];
    u32 s0,s1; tf2x32(k0,k1,0u,1u,s0,s1);
    u32 ka0,ka1; tf2x32(s0,s1,0u,1u,ka0,ka1);
    u32 t0,t1;  tf2x32(s0,s1,0u,0u,t0,t1);
    u32 kr0,kr1; tf2x32(t0,t1,0u,1u,kr0,kr1);
    u32 u0,u1;  tf2x32(t0,t1,0u,0u,u0,u1);
    u32 w0,w1;  tf2x32(u0,u1,0u,1u,w0,w1);
    u32* p=KST+6*(t-1);
    p[0]=ka0;p[1]=ka1;p[2]=kr0;p[3]=kr1;p[4]=w0;p[5]=w1;
  }
}

// ======================= k_all: round-6 structure (fused barrier, no pipelining),
// only the per-particle serial scan replaced by materialized CUM + binsearch ===
__global__ __launch_bounds__(TPB) void k_all(
    const float* __restrict__ obs, const float* __restrict__ inp,
    const float* __restrict__ mean, const float* __restrict__ icov,
    const float* __restrict__ coeff, const float* __restrict__ ecov,
    const float* __restrict__ refst, const float* __restrict__ Om,
    const float* __restrict__ ph, const float* __restrict__ Cm,
    float* wsf)
{
  const int tid=threadIdx.x;
  const int lane=tid&63;
  const int wib=tid>>6;                 // wave in block 0..3
  const int i=blockIdx.x*TPB+tid;       // particle id
  const int gw=i>>6;                    // global wave 0..127
  const bool lastblk=(blockIdx.x==NBLK-1);

  u32* BARC=(u32*)(wsf+WS_BARC); u32* BARG=(u32*)(wsf+WS_BARG);
  const u32* KI=(const u32*)(wsf+WS_KEYINIT);
  const u32* KST=(const u32*)(wsf+WS_KST);
  float* S1=wsf+WS_S1; float* S2=wsf+WS_S2; float* LLb=wsf+WS_LL;
  float* PM1=wsf+WS_PM1; float* PE1=wsf+WS_PE1;
  float* PM2=wsf+WS_PM2; float* PE2=wsf+WS_PE2;
  float* LWF=wsf+WS_LWF;
  u16* ANC=(u16*)(wsf+WS_ANC_F);
  float* TR=wsf+WS_TRACE;
  u32 g=0;

  __shared__ float CUM[8448];  // swizzled 8192-entry cumsum (SW(8191)=8446)
  __shared__ float EX1[128];
  __shared__ float EX2[128];
  __shared__ float MT[4];      // M1,T1,M2,T2

  float LEp[36];
  { float L0p[36];
    chol8(icov,L0p); chol8(ecov,LEp);
    float st[8];
    if(i==NS-1){ for(int d=0;d<8;d++) st[d]=refst[d]; }
    else {
      float eps[8];
      for(int d=0;d<8;d++) eps[d]=jax_normal_elem(KI[0],KI[1],(u32)(i*8+d));
      for(int d=0;d<8;d++){ float m=0.0f; for(int k=0;k<=d;k++) m+=eps[k]*L0p[d*(d+1)/2+k]; st[d]=mean[d]+m; }
    }
    for(int d=0;d<8;d++) TR[i*8+d]=st[d];

    float c_ll=4.0f*logf((float)(2.0*M_PI*0.1*0.1));
    float hc1=0.0f; for(int d=0;d<8;d++) hc1+=logf(LEp[d*(d+1)/2+d]);
    float hc2=4.0f*logf((float)(2.0*M_PI));
    const float SSQ=(float)(0.1*0.1);
    float lw=0.0f;

    for(int t=1;t<NSTEPS;t++){
      const u32* kp=KST+6*(t-1);
      u32 ka0=kp[0],ka1=kp[1],kr0=kp[2],kr1=kp[3],kst0=kp[4],kst1=kp[5];
      const int par=t&1;
      float* S1p=S1+par*NS; float* S2p=S2+par*NS; float* LLp=LLb+par*NS;
      float* PM1p=PM1+par*128; float* PE1p=PE1+par*128;
      float* PM2p=PM2+par*128; float* PE2p=PE2+par*128;

      // --- A: state-exact arithmetic (byte-identical to rounds 2-6) ---
      float z[12];
      for(int d=0;d<8;d++) z[d]=st[d];
      for(int k=0;k<4;k++) z[8+k]=inp[t*4+k];
      float ax[8]={0,0,0,0,0,0,0,0};
      for(int j=0;j<DBc;j++){
        float dot=0.0f;
        #pragma unroll
        for(int k=0;k<12;k++) dot+=z[k]*Om[j*12+k];
        float b=cosf(dot+ph[j]);
        #pragma unroll
        for(int d=0;d<8;d++) ax[d]+=b*coeff[d*DBc+j];
      }
      float S=0.0f;
      for(int d=0;d<8;d++){
        float m=0.0f;
        #pragma unroll
        for(int k=0;k<8;k++) m+=ax[k]*Cm[d*8+k];
        float r=obs[t*8+d]-m; S+=r*r;
      }
      float ll=(-0.5f*S)/SSQ - c_ll;
      float sol[8]; float q=0.0f;
      for(int d=0;d<8;d++){
        float s=refst[t*8+d]-ax[d];
        for(int k=0;k<d;k++) s-=LEp[d*(d+1)/2+k]*sol[k];
        sol[d]=s/LEp[d*(d+1)/2+d];
        q+=sol[d]*sol[d];
      }
      float h=(-0.5f*q - hc1) - hc2;
      float s1v=ll+lw, s2v=s1v+h;
      astore(S1p+i,s1v); astore(S2p+i,s2v); astore(LLp+i,ll);
      float m1=wave_max(s1v); float se1=wave_sum(expf(s1v-m1));
      float m2=wave_max(s2v); float se2=wave_sum(expf(s2v-m2));
      if(lane==0){ astore(PM1p+gw,m1); astore(PE1p+gw,se1);
                   astore(PM2p+gw,m2); astore(PE2p+gw,se2); }
      gridbar(BARC,BARG,g);   // the ONE fused barrier per step (r6 verbatim)

      // --- B: block-redundant online-softmax combine (r6 verbatim) ---
      if(wib<2){
        const float* PMp=(wib==0)?PM1p:PM2p;
        const float* PEp=(wib==0)?PE1p:PE2p;
        float* EX=(wib==0)?EX1:EX2;
        float a=aload(PMp+lane), b=aload(PMp+64+lane);
        float M=wave_max(fmaxf(a,b));
        float ga=aload(PEp+lane)*expf(a-M);
        float gb=aload(PEp+64+lane)*expf(b-M);
        float sA=wave_incl_scan(ga,lane);
        float totA=__shfl(sA,63,64);
        float sB=wave_incl_scan(gb,lane);
        float totB=__shfl(sB,63,64);
        EX[lane]=sA-ga;
        EX[64+lane]=totA+(sB-gb);
        if(lane==0){ MT[wib*2]=M; MT[wib*2+1]=totA+totB; }
      }
      __syncthreads();

      // --- materialize S1 serial in-wave cumsums (r6's exact c-sequence) ---
      if(tid<128){
        float Mx=MT[0];
        float c=EX1[tid];
        const float* Sb=S1p+(tid<<6);
        for(int j=0;j<64;j++){ c+=expf(aload(Sb+j)-Mx); CUM[SW((tid<<6)+j)]=c; }
      }
      __syncthreads();

      // --- D: resample (two-stage binsearch == r6's serial scan), propagate ---
      int aidx;
      if(i!=NS-1){
        float u1=jax_uniform01_scalar(ka0,ka1);
        float pos=((float)i+u1)*(1.0f/8192.0f);
        aidx=search_r6(EX1,CUM,pos*MT[1]);
      }
      if(lastblk){
        __syncthreads();   // all S1 searches in this block done; CUM reusable
        if(tid<128){
          float Mx=MT[2];
          float c=EX2[tid];
          const float* Sb=S2p+(tid<<6);
          for(int j=0;j<64;j++){ c+=expf(aload(Sb+j)-Mx); CUM[SW((tid<<6)+j)]=c; }
        }
        __syncthreads();
        if(i==NS-1){
          float u2=jax_uniform01_scalar(kr0,kr1);
          aidx=search_r6(EX2,CUM,u2*MT[3]);
        }
      }
      ANC[(size_t)(t-1)*NS+i]=(u16)aidx;

      if(i==NS-1){ for(int d=0;d<8;d++) st[d]=refst[t*8+d]; }
      else {
        float eps[8];
        for(int d=0;d<8;d++) eps[d]=jax_normal_elem(kst0,kst1,(u32)(i*8+d));
        for(int d=0;d<8;d++){ float m=0.0f; for(int k=0;k<=d;k++) m+=eps[k]*LEp[d*(d+1)/2+k]; st[d]=ax[d]+m; }
      }
      float S2n=0.0f;
      for(int d=0;d<8;d++){
        float m=0.0f;
        #pragma unroll
        for(int k=0;k<8;k++) m+=st[k]*Cm[d*8+k];
        float r=obs[t*8+d]-m; S2n+=r*r;
      }
      float lln=(-0.5f*S2n)/SSQ - c_ll;
      lw=lln-aload(LLp+aidx);
      float* TRt=TR+(size_t)t*NS*8;
      for(int d=0;d<8;d++) TRt[i*8+d]=st[d];
      // no barrier: S/LL/PM/PE parity-buffered; CUM overwrite separated by
      // gridbar's internal __syncthreads next iteration.
    }
    LWF[i]=lw;   // plain store; consumed by k_post (dispatch boundary)
  }
}

// ======================= k_post: final softmax + draw + backward + gather (r6 verbatim) =======================
__global__ __launch_bounds__(1024) void k_post(const float* __restrict__ wsf, float* __restrict__ out){
  __shared__ float sh[NS];
  __shared__ float r1[1024];
  __shared__ float r2[1024];
  __shared__ int IDXs[NSTEPS];
  int tid=threadIdx.x; int base=tid*8;
  const float* LW=wsf+WS_LWF;
  const u32* KF=(const u32*)(wsf+WS_KFIN);
  const u16* ANC=(const u16*)(wsf+WS_ANC_F);
  const float* TR=wsf+WS_TRACE;
  float v[8]; float m=-INFINITY;
  for(int k=0;k<8;k++){ v[k]=LW[base+k]; m=fmaxf(m,v[k]); }
  r1[tid]=m; __syncthreads();
  for(int off=512;off>0;off>>=1){ if(tid<off) r1[tid]=fmaxf(r1[tid],r1[tid+off]); __syncthreads(); }
  float M=r1[0]; __syncthreads();
  float e[8]; float cs=0.0f;
  for(int k=0;k<8;k++){ e[k]=expf(v[k]-M); cs+=e[k]; }
  r1[tid]=cs; __syncthreads();
  for(int off=512;off>0;off>>=1){ if(tid<off) r1[tid]+=r1[tid+off]; __syncthreads(); }
  float T=r1[0]; __syncthreads();
  float w[8]; float wcs=0.0f;
  for(int k=0;k<8;k++){ w[k]=e[k]/T; wcs+=w[k]; }
  float* src=r1; float* dst=r2;
  src[tid]=wcs; __syncthreads();
  for(int off=1;off<1024;off<<=1){
    float x=src[tid]; if(tid>=off) x+=src[tid-off];
    dst[tid]=x; __syncthreads(); float* tmp=src; src=dst; dst=tmp;
  }
  float excl=(tid==0)?0.0f:src[tid-1];
  __syncthreads();
  float run=excl;
  for(int k=0;k<8;k++){ run+=w[k]; sh[base+k]=run; }
  __syncthreads();
  if(tid==0){
    float u=jax_uniform01_scalar(KF[0],KF[1]);
    int b=bsearch8192(sh,u);
    IDXs[NSTEPS-1]=b;
    for(int r=NSTEPS-2;r>=0;r--){ b=(int)ANC[(size_t)r*NS+b]; IDXs[r]=b; }
  }
  __syncthreads();
  for(int e2=tid;e2<NSTEPS*8;e2+=1024){
    int t=e2>>3,d=e2&7;
    out[e2]=TR[((size_t)t*NS+IDXs[t])*8+d];
  }
}

// ======================= launch =======================
extern "C" void kernel_launch(void* const* d_in, const int* in_sizes, int n_in,
                              void* d_out, int out_size, void* d_ws, size_t ws_size,
                              hipStream_t stream) {
  const float* obs  =(const float*)d_in[0];
  const float* inp  =(const float*)d_in[1];
  const float* mean =(const float*)d_in[2];
  const float* icov =(const float*)d_in[3];
  const float* coeff=(const float*)d_in[4];
  const float* ecov =(const float*)d_in[5];
  const float* refst=(const float*)d_in[6];
  const float* Om   =(const float*)d_in[7];
  const float* ph   =(const float*)d_in[8];
  const float* Cm   =(const float*)d_in[9];
  const int*   seedp=(const int*)d_in[10];
  float* wsf=(float*)d_ws;
  float* out=(float*)d_out;

  hipLaunchKernelGGL(k_pre, dim3(1), dim3(256), 0, stream, seedp, wsf);

  void* args[]={ (void*)&obs,(void*)&inp,(void*)&mean,(void*)&icov,(void*)&coeff,
                 (void*)&ecov,(void*)&refst,(void*)&Om,(void*)&ph,(void*)&Cm,
                 (void*)&wsf };
  hipLaunchCooperativeKernel((void*)k_all, dim3(NBLK), dim3(TPB), args, 0, stream);

  hipLaunchKernelGGL(k_post, dim3(1), dim3(1024), 0, stream, wsf, out);
}

// Round 10
// 9831.138 us; speedup vs baseline: 1.2498x; 1.2498x over previous
//
#include <hip/hip_runtime.h>
#include <stdint.h>
#include <math.h>

#define NS 8192
#define NSTEPS 200
#define DBc 128

typedef unsigned int u32;
typedef unsigned short u16;

// ws float-offset layout (float slots), total ~29.5 MB
#define WS_KEYINIT 64      // u32[2]
#define WS_KFIN   66       // u32[2]
#define WS_KC     128      // u32[400]
#define WS_KST    640      // u32[6*199] -> ends 1834
#define WS_IDX    2048     // int[200]
#define WS_LL     4096                    // [200][8192] -> ends 1642496
#define WS_H      (WS_LL+NSTEPS*NS)       // -> ends 3280896
#define WS_LLN    (WS_H+NSTEPS*NS)        // -> ends 4919296
#define WS_ANC_F  (WS_LLN+NSTEPS*NS)      // u16[199*8192] = 815104 slots -> ends 5734400
#define WS_CKPT   (WS_ANC_F+(NSTEPS-1)*NS/2)  // [25][8192][8] -> ends 7372800

// ======================= threefry2x32-20 (validated r1-r9) =======================
__device__ __forceinline__ u32 rotl32(u32 v, int r){ return (v<<r)|(v>>(32-r)); }

__device__ __forceinline__ void tf2x32(u32 k0,u32 k1,u32 c0,u32 c1,u32&o0,u32&o1){
  u32 ks2 = k0^k1^0x1BD11BDAu;
  u32 x0=c0+k0, x1=c1+k1;
#define TFR(R) { x0+=x1; x1=rotl32(x1,(R)); x1^=x0; }
  TFR(13) TFR(15) TFR(26) TFR(6)
  x0+=k1;  x1+=ks2+1u;
  TFR(17) TFR(29) TFR(16) TFR(24)
  x0+=ks2; x1+=k0+2u;
  TFR(13) TFR(15) TFR(26) TFR(6)
  x0+=k0;  x1+=k1+3u;
  TFR(17) TFR(29) TFR(16) TFR(24)
  x0+=k1;  x1+=ks2+4u;
  TFR(13) TFR(15) TFR(26) TFR(6)
  x0+=ks2; x1+=k0+5u;
#undef TFR
  o0=x0; o1=x1;
}

__device__ __forceinline__ u32 jax_bits_elem(u32 k0,u32 k1,u32 i){
  u32 a,b; tf2x32(k0,k1,0u,i,a,b); return a^b;
}

__device__ __forceinline__ float bits_to_f01(u32 bits){
  return __uint_as_float((bits>>9)|0x3f800000u) - 1.0f;
}

__device__ __forceinline__ float log1pf_acc(float a){
#pragma clang fp contract(off)
  float u = 1.0f + a;
  if (u == 1.0f) return a;
  float l = logf(u);
  return l * (a / (u - 1.0f));
}

__device__ __forceinline__ float erfinv_xla(float x){
#pragma clang fp contract(off)
  float a = -(x*x);
  float w = -log1pf_acc(a);
  float p;
  if (w < 5.0f){
    w = w - 2.5f;
    p = 2.81022636e-08f;
    p = 3.43273939e-07f + p*w;
    p = -3.5233877e-06f + p*w;
    p = -4.39150654e-06f + p*w;
    p = 0.00021858087f  + p*w;
    p = -0.00125372503f + p*w;
    p = -0.00417768164f + p*w;
    p = 0.246640727f    + p*w;
    p = 1.50140941f     + p*w;
  } else {
    w = sqrtf(w) - 3.0f;
    p = -0.000200214257f;
    p = 0.000100950558f + p*w;
    p = 0.00134934322f  + p*w;
    p = -0.00367342844f + p*w;
    p = 0.00573950773f  + p*w;
    p = -0.0076224613f  + p*w;
    p = 0.00943887047f  + p*w;
    p = 1.00167406f     + p*w;
    p = 2.83297682f     + p*w;
  }
  return p*x;
}

__device__ __forceinline__ float jax_normal_elem(u32 k0,u32 k1,u32 i){
#pragma clang fp contract(off)
  float f = bits_to_f01(jax_bits_elem(k0,k1,i));
  float u = f*2.0f + (-0.99999994039535522f);
  u = fmaxf(-0.99999994039535522f, u);
  return 1.41421356237309515f * erfinv_xla(u);
}

__device__ __forceinline__ float jax_uniform01_scalar(u32 k0,u32 k1){
  return bits_to_f01(jax_bits_elem(k0,k1,0u));
}

// ======================= wave helpers =======================
__device__ __forceinline__ float wave_max(float v){
  #pragma unroll
  for(int m=1;m<64;m<<=1) v=fmaxf(v,__shfl_xor(v,m,64));
  return v;
}
__device__ __forceinline__ float wave_incl_scan(float v,int lane){
  #pragma unroll
  for(int o=1;o<64;o<<=1){ float u=__shfl_up(v,o,64); if(lane>=o) v+=u; }
  return v;
}

__device__ void chol8(const float* A,float* L){
  for(int c=0;c<8;c++){
    for(int r=c;r<8;r++){
      float s=A[r*8+c];
      for(int k=0;k<c;k++) s-=L[r*(r+1)/2+k]*L[c*(c+1)/2+k];
      L[r*(r+1)/2+c]=(r==c)? sqrtf(s) : s/L[c*(c+1)/2+c];
    }
  }
}

// ======================= k_pre: key chain (validated r5-r9) =======================
__global__ __launch_bounds__(256) void k_pre(const int* __restrict__ seedp, float* wsf){
  u32* KI=(u32*)(wsf+WS_KEYINIT); u32* KF=(u32*)(wsf+WS_KFIN);
  u32* KC=(u32*)(wsf+WS_KC); u32* KST=(u32*)(wsf+WS_KST);
  int tid=threadIdx.x;
  if(tid==0){
    u32 s=(u32)seedp[0];
    u32 a,b;
    tf2x32(0u,s,0u,0u,a,b); KC[0]=a; KC[1]=b;      // key_0 = split(key).child0
    tf2x32(0u,s,0u,1u,a,b); KI[0]=a; KI[1]=b;      // key_init = child1
    for(int t=1;t<NSTEPS;t++){
      tf2x32(KC[2*(t-1)],KC[2*(t-1)+1],0u,0u,a,b);
      KC[2*t]=a; KC[2*t+1]=b;
    }
    KF[0]=KC[2*(NSTEPS-1)]; KF[1]=KC[2*(NSTEPS-1)+1];
  }
  __syncthreads();
  int t=tid;
  if(t>=1 && t<NSTEPS){
    u32 k0=KC[2*(t-1)], k1=KC[2*(t-1)+1];
    u32 s0,s1; tf2x32(k0,k1,0u,1u,s0,s1);          // key_step
    u32 ka0,ka1; tf2x32(s0,s1,0u,1u,ka0,ka1);      // k_anc
    u32 t0,t1;  tf2x32(s0,s1,0u,0u,t0,t1);
    u32 kr0,kr1; tf2x32(t0,t1,0u,1u,kr0,kr1);      // k_ref
    u32 u0,u1;  tf2x32(t0,t1,0u,0u,u0,u1);
    u32 w0,w1;  tf2x32(u0,u1,0u,1u,w0,w1);         // k_state
    u32* p=KST+6*(t-1);
    p[0]=ka0;p[1]=ka1;p[2]=kr0;p[3]=kr1;p[4]=w0;p[5]=w1;
  }
}

// ======================= k_state: all 199 steps per particle, no barriers ====
// State arithmetic byte-identical to rounds 2-9. Stores ll/h/lln + checkpoints.
__global__ __launch_bounds__(64) void k_state(
    const float* __restrict__ obs, const float* __restrict__ inp,
    const float* __restrict__ mean, const float* __restrict__ icov,
    const float* __restrict__ coeff, const float* __restrict__ ecov,
    const float* __restrict__ refst, const float* __restrict__ Om,
    const float* __restrict__ ph, const float* __restrict__ Cm,
    float* wsf)
{
  const int i=blockIdx.x*64+threadIdx.x;
  const u32* KI=(const u32*)(wsf+WS_KEYINIT);
  const u32* KST=(const u32*)(wsf+WS_KST);
  float* LL=wsf+WS_LL; float* H=wsf+WS_H; float* LLN=wsf+WS_LLN;
  float* CKPT=wsf+WS_CKPT;

  float LEp[36];
  { float L0p[36];
    chol8(icov,L0p); chol8(ecov,LEp);
    float st[8];
    if(i==NS-1){ for(int d=0;d<8;d++) st[d]=refst[d]; }
    else {
      float eps[8];
      for(int d=0;d<8;d++) eps[d]=jax_normal_elem(KI[0],KI[1],(u32)(i*8+d));
      for(int d=0;d<8;d++){ float m=0.0f; for(int k=0;k<=d;k++) m+=eps[k]*L0p[d*(d+1)/2+k]; st[d]=mean[d]+m; }
    }
    { float* ck=CKPT+(size_t)i*8;     // checkpoint row 0 = state at t=0
      for(int d=0;d<8;d++) ck[d]=st[d]; }

    float c_ll=4.0f*logf((float)(2.0*M_PI*0.1*0.1));
    float hc1=0.0f; for(int d=0;d<8;d++) hc1+=logf(LEp[d*(d+1)/2+d]);
    float hc2=4.0f*logf((float)(2.0*M_PI));
    const float SSQ=(float)(0.1*0.1);

    for(int t=1;t<NSTEPS;t++){
      // --- A: exact ---
      float z[12];
      for(int d=0;d<8;d++) z[d]=st[d];
      for(int k=0;k<4;k++) z[8+k]=inp[t*4+k];
      float ax[8]={0,0,0,0,0,0,0,0};
      for(int j=0;j<DBc;j++){
        float dot=0.0f;
        #pragma unroll
        for(int k=0;k<12;k++) dot+=z[k]*Om[j*12+k];
        float b=cosf(dot+ph[j]);
        #pragma unroll
        for(int d=0;d<8;d++) ax[d]+=b*coeff[d*DBc+j];
      }
      float S=0.0f;
      for(int d=0;d<8;d++){
        float m=0.0f;
        #pragma unroll
        for(int k=0;k<8;k++) m+=ax[k]*Cm[d*8+k];
        float r=obs[t*8+d]-m; S+=r*r;
      }
      float ll=(-0.5f*S)/SSQ - c_ll;
      float sol[8]; float q=0.0f;
      for(int d=0;d<8;d++){
        float s=refst[t*8+d]-ax[d];
        for(int k=0;k<d;k++) s-=LEp[d*(d+1)/2+k]*sol[k];
        sol[d]=s/LEp[d*(d+1)/2+d];
        q+=sol[d]*sol[d];
      }
      float h=(-0.5f*q - hc1) - hc2;
      LL[(size_t)t*NS+i]=ll;
      H[(size_t)t*NS+i]=h;

      // --- P: exact ---
      if(i==NS-1){ for(int d=0;d<8;d++) st[d]=refst[t*8+d]; }
      else {
        const u32* kp=KST+6*(t-1);
        float eps[8];
        for(int d=0;d<8;d++) eps[d]=jax_normal_elem(kp[4],kp[5],(u32)(i*8+d));
        for(int d=0;d<8;d++){ float m=0.0f; for(int k=0;k<=d;k++) m+=eps[k]*LEp[d*(d+1)/2+k]; st[d]=ax[d]+m; }
      }
      float S2n=0.0f;
      for(int d=0;d<8;d++){
        float m=0.0f;
        #pragma unroll
        for(int k=0;k<8;k++) m+=st[k]*Cm[d*8+k];
        float r=obs[t*8+d]-m; S2n+=r*r;
      }
      float lln=(-0.5f*S2n)/SSQ - c_ll;
      LLN[(size_t)t*NS+i]=lln;

      if((t&7)==0){
        float* ck=CKPT+((size_t)(t>>3)*NS+i)*8;
        for(int d=0;d<8;d++) ck[d]=st[d];
      }
    }
  }
}

// ======================= k_weights: sequential resampling chain, one block ====
__global__ __launch_bounds__(1024) void k_weights(float* wsf){
  const int tid=threadIdx.x;
  const int lane=tid&63;
  const int wid=tid>>6;       // 0..15
  const int base=tid*8;
  const u32* KST=(const u32*)(wsf+WS_KST);
  const u32* KF=(const u32*)(wsf+WS_KFIN);
  const float* LL=wsf+WS_LL;
  const float* H=wsf+WS_H;
  const float* LLN=wsf+WS_LLN;
  u16* ANC=(u16*)(wsf+WS_ANC_F);
  int* IDX=(int*)(wsf+WS_IDX);

  __shared__ float CUM[NS];                 // 32 KB
  __shared__ float WMX[16],WMX2[16],WSM[16],WSM2[16];

  float lw[8];
  #pragma unroll
  for(int k=0;k<8;k++) lw[k]=0.0f;

  for(int t=1;t<NSTEPS;t++){
    const u32* kp=KST+6*(t-1);
    const float* LLt=LL+(size_t)t*NS;
    const float* Ht=H+(size_t)t*NS;
    const float* LLNt=LLN+(size_t)t*NS;

    float s1v[8],s2v[8];
    float m1=-INFINITY,m2=-INFINITY;
    #pragma unroll
    for(int k=0;k<8;k++){
      float llv=LLt[base+k], hv=Ht[base+k];
      s1v[k]=llv+lw[k];
      s2v[k]=s1v[k]+hv;
      m1=fmaxf(m1,s1v[k]); m2=fmaxf(m2,s2v[k]);
    }
    float wm1=wave_max(m1), wm2=wave_max(m2);
    if(lane==0){ WMX[wid]=wm1; WMX2[wid]=wm2; }
    __syncthreads();
    float M1=WMX[0],M2=WMX2[0];
    #pragma unroll
    for(int w=1;w<16;w++){ M1=fmaxf(M1,WMX[w]); M2=fmaxf(M2,WMX2[w]); }

    float e1[8],e2[8]; float ts1=0.0f,ts2=0.0f;
    #pragma unroll
    for(int k=0;k<8;k++){
      e1[k]=expf(s1v[k]-M1); ts1+=e1[k];
      e2[k]=expf(s2v[k]-M2); ts2+=e2[k];
    }
    float is1=wave_incl_scan(ts1,lane);
    float is2=wave_incl_scan(ts2,lane);
    if(lane==63){ WSM[wid]=is1; WSM2[wid]=is2; }
    __syncthreads();
    float T1=0.0f,T2=0.0f,woff1=0.0f,woff2=0.0f;
    #pragma unroll
    for(int w=0;w<16;w++){
      float a=WSM[w], b=WSM2[w];
      T1+=a; T2+=b;
      if(w<wid){ woff1+=a; woff2+=b; }
    }
    float excl1=woff1+(is1-ts1);
    float excl2=woff2+(is2-ts2);

    // --- CUM for S1 (raw scale, r6-style tau = pos*T) ---
    { float run=excl1;
      #pragma unroll
      for(int k=0;k<8;k++){ run+=e1[k]; CUM[base+k]=run; } }
    __syncthreads();

    float lwn[8];
    float u1=jax_uniform01_scalar(kp[0],kp[1]);
    #pragma unroll
    for(int k=0;k<8;k++){
      int i=base+k;
      if(i!=NS-1){
        float pos=((float)i+u1)*(1.0f/8192.0f);
        float tau=pos*T1;
        int lo=0,hi=NS;
        while(lo<hi){ int mid=(lo+hi)>>1; if(CUM[mid]<tau) lo=mid+1; else hi=mid; }
        if(lo>NS-1) lo=NS-1;
        ANC[(size_t)(t-1)*NS+i]=(u16)lo;
        lwn[k]=LLNt[i]-LLt[lo];
      }
    }
    __syncthreads();     // S1 searches done before CUM reuse

    // --- CUM for S2 (only the reference draw needs it) ---
    { float run=excl2;
      #pragma unroll
      for(int k=0;k<8;k++){ run+=e2[k]; CUM[base+k]=run; } }
    __syncthreads();
    if(tid==1023){
      float u2=jax_uniform01_scalar(kp[2],kp[3]);
      float tau=u2*T2;
      int lo=0,hi=NS;
      while(lo<hi){ int mid=(lo+hi)>>1; if(CUM[mid]<tau) lo=mid+1; else hi=mid; }
      if(lo>NS-1) lo=NS-1;
      ANC[(size_t)(t-1)*NS+(NS-1)]=(u16)lo;
      lwn[7]=LLNt[NS-1]-LLt[lo];
    }
    #pragma unroll
    for(int k=0;k<8;k++) lw[k]=lwn[k];
    __syncthreads();     // protect CUM until next iteration's writes
  }

  // ===== final softmax over lw, draw, backward chain =====
  {
    float m=-INFINITY;
    #pragma unroll
    for(int k=0;k<8;k++) m=fmaxf(m,lw[k]);
    float wm=wave_max(m);
    if(lane==0) WMX[wid]=wm;
    __syncthreads();
    float M=WMX[0];
    #pragma unroll
    for(int w=1;w<16;w++) M=fmaxf(M,WMX[w]);
    float e[8]; float ts=0.0f;
    #pragma unroll
    for(int k=0;k<8;k++){ e[k]=expf(lw[k]-M); ts+=e[k]; }
    float is=wave_incl_scan(ts,lane);
    if(lane==63) WSM[wid]=is;
    __syncthreads();
    float T=0.0f,woff=0.0f;
    #pragma unroll
    for(int w=0;w<16;w++){ T+=WSM[w]; if(w<wid) woff+=WSM[w]; }
    float run=woff+(is-ts);
    #pragma unroll
    for(int k=0;k<8;k++){ run+=e[k]; CUM[base+k]=run; }
    __syncthreads();
    if(tid==0){
      float u=jax_uniform01_scalar(KF[0],KF[1]);
      float tau=u*T;
      int lo=0,hi=NS;
      while(lo<hi){ int mid=(lo+hi)>>1; if(CUM[mid]<tau) lo=mid+1; else hi=mid; }
      if(lo>NS-1) lo=NS-1;
      int b=lo;
      IDX[NSTEPS-1]=b;
      for(int r=NSTEPS-2;r>=0;r--){ b=(int)ANC[(size_t)r*NS+b]; IDX[r]=b; }
    }
  }
}

// ======================= k_replay: checkpoint replay + gather ================
// Re-runs the EXACT per-thread state recurrence from the nearest checkpoint,
// so outputs are bit-identical to k_state's states (unlike r1's reordered replay).
__global__ __launch_bounds__(256) void k_replay(
    const float* __restrict__ inp, const float* __restrict__ refst,
    const float* __restrict__ ecov, const float* __restrict__ Om,
    const float* __restrict__ ph, const float* __restrict__ coeff,
    const float* __restrict__ wsf, float* __restrict__ out)
{
  int task=blockIdx.x*blockDim.x+threadIdx.x;
  if(task>=NSTEPS) return;
  const int* IDX=(const int*)(wsf+WS_IDX);
  const u32* KST=(const u32*)(wsf+WS_KST);
  const float* CKPT=wsf+WS_CKPT;
  int t=task, p=IDX[t];
  if(p==NS-1){ for(int d=0;d<8;d++) out[t*8+d]=refst[t*8+d]; return; }
  float LEp[36]; chol8(ecov,LEp);
  int c=(t>>3)<<3;
  const float* ck=CKPT+((size_t)(t>>3)*NS+p)*8;
  float st[8];
  for(int d=0;d<8;d++) st[d]=ck[d];
  for(int s=c+1;s<=t;s++){
    float z[12];
    for(int d=0;d<8;d++) z[d]=st[d];
    for(int k=0;k<4;k++) z[8+k]=inp[s*4+k];
    float ax[8]={0,0,0,0,0,0,0,0};
    for(int j=0;j<DBc;j++){
      float dot=0.0f;
      #pragma unroll
      for(int k=0;k<12;k++) dot+=z[k]*Om[j*12+k];
      float b=cosf(dot+ph[j]);
      #pragma unroll
      for(int d=0;d<8;d++) ax[d]+=b*coeff[d*DBc+j];
    }
    const u32* kp=KST+6*(s-1);
    float eps[8];
    for(int d=0;d<8;d++) eps[d]=jax_normal_elem(kp[4],kp[5],(u32)(p*8+d));
    for(int d=0;d<8;d++){ float m=0.0f; for(int k=0;k<=d;k++) m+=eps[k]*LEp[d*(d+1)/2+k]; st[d]=ax[d]+m; }
  }
  for(int d=0;d<8;d++) out[t*8+d]=st[d];
}

// ======================= launch =======================
extern "C" void kernel_launch(void* const* d_in, const int* in_sizes, int n_in,
                              void* d_out, int out_size, void* d_ws, size_t ws_size,
                              hipStream_t stream) {
  const float* obs  =(const float*)d_in[0];
  const float* inp  =(const float*)d_in[1];
  const float* mean =(const float*)d_in[2];
  const float* icov =(const float*)d_in[3];
  const float* coeff=(const float*)d_in[4];
  const float* ecov =(const float*)d_in[5];
  const float* refst=(const float*)d_in[6];
  const float* Om   =(const float*)d_in[7];
  const float* ph   =(const float*)d_in[8];
  const float* Cm   =(const float*)d_in[9];
  const int*   seedp=(const int*)d_in[10];
  float* wsf=(float*)d_ws;
  float* out=(float*)d_out;

  hipLaunchKernelGGL(k_pre, dim3(1), dim3(256), 0, stream, seedp, wsf);
  hipLaunchKernelGGL(k_state, dim3(NS/64), dim3(64), 0, stream,
                     obs, inp, mean, icov, coeff, ecov, refst, Om, ph, Cm, wsf);
  hipLaunchKernelGGL(k_weights, dim3(1), dim3(1024), 0, stream, wsf);
  hipLaunchKernelGGL(k_replay, dim3(1), dim3(256), 0, stream,
                     inp, refst, ecov, Om, ph, coeff, wsf, out);
}

// Round 12
// 9790.589 us; speedup vs baseline: 1.2550x; 1.0041x over previous
//
#include <hip/hip_runtime.h>
#include <stdint.h>
#include <math.h>

#define NS 8192
#define NSTEPS 200
#define DBc 128

typedef unsigned int u32;
typedef unsigned short u16;

// ws float-offset layout (float slots), total ~29.5 MB
#define WS_KEYINIT 64      // u32[2]
#define WS_KFIN   66       // u32[2]
#define WS_KC     128      // u32[400]
#define WS_KST    640      // u32[6*199] -> ends 1834
#define WS_IDX    2048     // int[200]
#define WS_LL     4096                    // [200][8192] -> ends 1642496
#define WS_H      (WS_LL+NSTEPS*NS)       // -> ends 3280896
#define WS_LLN    (WS_H+NSTEPS*NS)        // -> ends 4919296
#define WS_ANC_F  (WS_LLN+NSTEPS*NS)      // u16[199*8192] = 815104 slots -> ends 5734400
#define WS_CKPT   (WS_ANC_F+(NSTEPS-1)*NS/2)  // [25][8192][8] -> ends 7372800

// ======================= threefry2x32-20 (validated r1-r10) =======================
__device__ __forceinline__ u32 rotl32(u32 v, int r){ return (v<<r)|(v>>(32-r)); }

__device__ __forceinline__ void tf2x32(u32 k0,u32 k1,u32 c0,u32 c1,u32&o0,u32&o1){
  u32 ks2 = k0^k1^0x1BD11BDAu;
  u32 x0=c0+k0, x1=c1+k1;
#define TFR(R) { x0+=x1; x1=rotl32(x1,(R)); x1^=x0; }
  TFR(13) TFR(15) TFR(26) TFR(6)
  x0+=k1;  x1+=ks2+1u;
  TFR(17) TFR(29) TFR(16) TFR(24)
  x0+=ks2; x1+=k0+2u;
  TFR(13) TFR(15) TFR(26) TFR(6)
  x0+=k0;  x1+=k1+3u;
  TFR(17) TFR(29) TFR(16) TFR(24)
  x0+=k1;  x1+=ks2+4u;
  TFR(13) TFR(15) TFR(26) TFR(6)
  x0+=ks2; x1+=k0+5u;
#undef TFR
  o0=x0; o1=x1;
}

__device__ __forceinline__ u32 jax_bits_elem(u32 k0,u32 k1,u32 i){
  u32 a,b; tf2x32(k0,k1,0u,i,a,b); return a^b;
}

__device__ __forceinline__ float bits_to_f01(u32 bits){
  return __uint_as_float((bits>>9)|0x3f800000u) - 1.0f;
}

__device__ __forceinline__ float log1pf_acc(float a){
#pragma clang fp contract(off)
  float u = 1.0f + a;
  if (u == 1.0f) return a;
  float l = logf(u);
  return l * (a / (u - 1.0f));
}

__device__ __forceinline__ float erfinv_xla(float x){
#pragma clang fp contract(off)
  float a = -(x*x);
  float w = -log1pf_acc(a);
  float p;
  if (w < 5.0f){
    w = w - 2.5f;
    p = 2.81022636e-08f;
    p = 3.43273939e-07f + p*w;
    p = -3.5233877e-06f + p*w;
    p = -4.39150654e-06f + p*w;
    p = 0.00021858087f  + p*w;
    p = -0.00125372503f + p*w;
    p = -0.00417768164f + p*w;
    p = 0.246640727f    + p*w;
    p = 1.50140941f     + p*w;
  } else {
    w = sqrtf(w) - 3.0f;
    p = -0.000200214257f;
    p = 0.000100950558f + p*w;
    p = 0.00134934322f  + p*w;
    p = -0.00367342844f + p*w;
    p = 0.00573950773f  + p*w;
    p = -0.0076224613f  + p*w;
    p = 0.00943887047f  + p*w;
    p = 1.00167406f     + p*w;
    p = 2.83297682f     + p*w;
  }
  return p*x;
}

__device__ __forceinline__ float jax_normal_elem(u32 k0,u32 k1,u32 i){
#pragma clang fp contract(off)
  float f = bits_to_f01(jax_bits_elem(k0,k1,i));
  float u = f*2.0f + (-0.99999994039535522f);
  u = fmaxf(-0.99999994039535522f, u);
  return 1.41421356237309515f * erfinv_xla(u);
}

__device__ __forceinline__ float jax_uniform01_scalar(u32 k0,u32 k1){
  return bits_to_f01(jax_bits_elem(k0,k1,0u));
}

// ======================= wave helpers =======================
__device__ __forceinline__ float wave_max(float v){
  #pragma unroll
  for(int m=1;m<64;m<<=1) v=fmaxf(v,__shfl_xor(v,m,64));
  return v;
}
__device__ __forceinline__ float wave_incl_scan(float v,int lane){
  #pragma unroll
  for(int o=1;o<64;o<<=1){ float u=__shfl_up(v,o,64); if(lane>=o) v+=u; }
  return v;
}

__device__ void chol8(const float* A,float* L){
  for(int c=0;c<8;c++){
    for(int r=c;r<8;r++){
      float s=A[r*8+c];
      for(int k=0;k<c;k++) s-=L[r*(r+1)/2+k]*L[c*(c+1)/2+k];
      L[r*(r+1)/2+c]=(r==c)? sqrtf(s) : s/L[c*(c+1)/2+c];
    }
  }
}

// ======================= k_pre: key chain (validated r5-r10) =======================
__global__ __launch_bounds__(256) void k_pre(const int* __restrict__ seedp, float* wsf){
  u32* KI=(u32*)(wsf+WS_KEYINIT); u32* KF=(u32*)(wsf+WS_KFIN);
  u32* KC=(u32*)(wsf+WS_KC); u32* KST=(u32*)(wsf+WS_KST);
  int tid=threadIdx.x;
  if(tid==0){
    u32 s=(u32)seedp[0];
    u32 a,b;
    tf2x32(0u,s,0u,0u,a,b); KC[0]=a; KC[1]=b;      // key_0 = split(key).child0
    tf2x32(0u,s,0u,1u,a,b); KI[0]=a; KI[1]=b;      // key_init = child1
    for(int t=1;t<NSTEPS;t++){
      tf2x32(KC[2*(t-1)],KC[2*(t-1)+1],0u,0u,a,b);
      KC[2*t]=a; KC[2*t+1]=b;
    }
    KF[0]=KC[2*(NSTEPS-1)]; KF[1]=KC[2*(NSTEPS-1)+1];
  }
  __syncthreads();
  int t=tid;
  if(t>=1 && t<NSTEPS){
    u32 k0=KC[2*(t-1)], k1=KC[2*(t-1)+1];
    u32 s0,s1; tf2x32(k0,k1,0u,1u,s0,s1);          // key_step
    u32 ka0,ka1; tf2x32(s0,s1,0u,1u,ka0,ka1);      // k_anc
    u32 t0,t1;  tf2x32(s0,s1,0u,0u,t0,t1);
    u32 kr0,kr1; tf2x32(t0,t1,0u,1u,kr0,kr1);      // k_ref
    u32 u0,u1;  tf2x32(t0,t1,0u,0u,u0,u1);
    u32 w0,w1;  tf2x32(u0,u1,0u,1u,w0,w1);         // k_state
    u32* p=KST+6*(t-1);
    p[0]=ka0;p[1]=ka1;p[2]=kr0;p[3]=kr1;p[4]=w0;p[5]=w1;
  }
}

// ======================= k_state: r10 VERBATIM (frozen — transcendental bits) ====
__global__ __launch_bounds__(64) void k_state(
    const float* __restrict__ obs, const float* __restrict__ inp,
    const float* __restrict__ mean, const float* __restrict__ icov,
    const float* __restrict__ coeff, const float* __restrict__ ecov,
    const float* __restrict__ refst, const float* __restrict__ Om,
    const float* __restrict__ ph, const float* __restrict__ Cm,
    float* wsf)
{
  const int i=blockIdx.x*64+threadIdx.x;
  const u32* KI=(const u32*)(wsf+WS_KEYINIT);
  const u32* KST=(const u32*)(wsf+WS_KST);
  float* LL=wsf+WS_LL; float* H=wsf+WS_H; float* LLN=wsf+WS_LLN;
  float* CKPT=wsf+WS_CKPT;

  float LEp[36];
  { float L0p[36];
    chol8(icov,L0p); chol8(ecov,LEp);
    float st[8];
    if(i==NS-1){ for(int d=0;d<8;d++) st[d]=refst[d]; }
    else {
      float eps[8];
      for(int d=0;d<8;d++) eps[d]=jax_normal_elem(KI[0],KI[1],(u32)(i*8+d));
      for(int d=0;d<8;d++){ float m=0.0f; for(int k=0;k<=d;k++) m+=eps[k]*L0p[d*(d+1)/2+k]; st[d]=mean[d]+m; }
    }
    { float* ck=CKPT+(size_t)i*8;     // checkpoint row 0 = state at t=0
      for(int d=0;d<8;d++) ck[d]=st[d]; }

    float c_ll=4.0f*logf((float)(2.0*M_PI*0.1*0.1));
    float hc1=0.0f; for(int d=0;d<8;d++) hc1+=logf(LEp[d*(d+1)/2+d]);
    float hc2=4.0f*logf((float)(2.0*M_PI));
    const float SSQ=(float)(0.1*0.1);

    for(int t=1;t<NSTEPS;t++){
      // --- A: exact ---
      float z[12];
      for(int d=0;d<8;d++) z[d]=st[d];
      for(int k=0;k<4;k++) z[8+k]=inp[t*4+k];
      float ax[8]={0,0,0,0,0,0,0,0};
      for(int j=0;j<DBc;j++){
        float dot=0.0f;
        #pragma unroll
        for(int k=0;k<12;k++) dot+=z[k]*Om[j*12+k];
        float b=cosf(dot+ph[j]);
        #pragma unroll
        for(int d=0;d<8;d++) ax[d]+=b*coeff[d*DBc+j];
      }
      float S=0.0f;
      for(int d=0;d<8;d++){
        float m=0.0f;
        #pragma unroll
        for(int k=0;k<8;k++) m+=ax[k]*Cm[d*8+k];
        float r=obs[t*8+d]-m; S+=r*r;
      }
      float ll=(-0.5f*S)/SSQ - c_ll;
      float sol[8]; float q=0.0f;
      for(int d=0;d<8;d++){
        float s=refst[t*8+d]-ax[d];
        for(int k=0;k<d;k++) s-=LEp[d*(d+1)/2+k]*sol[k];
        sol[d]=s/LEp[d*(d+1)/2+d];
        q+=sol[d]*sol[d];
      }
      float h=(-0.5f*q - hc1) - hc2;
      LL[(size_t)t*NS+i]=ll;
      H[(size_t)t*NS+i]=h;

      // --- P: exact ---
      if(i==NS-1){ for(int d=0;d<8;d++) st[d]=refst[t*8+d]; }
      else {
        const u32* kp=KST+6*(t-1);
        float eps[8];
        for(int d=0;d<8;d++) eps[d]=jax_normal_elem(kp[4],kp[5],(u32)(i*8+d));
        for(int d=0;d<8;d++){ float m=0.0f; for(int k=0;k<=d;k++) m+=eps[k]*LEp[d*(d+1)/2+k]; st[d]=ax[d]+m; }
      }
      float S2n=0.0f;
      for(int d=0;d<8;d++){
        float m=0.0f;
        #pragma unroll
        for(int k=0;k<8;k++) m+=st[k]*Cm[d*8+k];
        float r=obs[t*8+d]-m; S2n+=r*r;
      }
      float lln=(-0.5f*S2n)/SSQ - c_ll;
      LLN[(size_t)t*NS+i]=lln;

      if((t&7)==0){
        float* ck=CKPT+((size_t)(t>>3)*NS+i)*8;
        for(int d=0;d<8;d++) ck[d]=st[d];
      }
    }
  }
}

// ======================= k_weights: sequential resampling chain, one block ====
// r10 arithmetic statements verbatim; changes: CUM2 second buffer (6->3 syncs),
// register prefetch of next step's LL/H/LLN rows issued during search phase.
__global__ __launch_bounds__(1024) void k_weights(float* wsf){
  const int tid=threadIdx.x;
  const int lane=tid&63;
  const int wid=tid>>6;       // 0..15
  const int base=tid*8;
  const u32* KST=(const u32*)(wsf+WS_KST);
  const u32* KF=(const u32*)(wsf+WS_KFIN);
  const float* LL=wsf+WS_LL;
  const float* H=wsf+WS_H;
  const float* LLN=wsf+WS_LLN;
  u16* ANC=(u16*)(wsf+WS_ANC_F);
  int* IDX=(int*)(wsf+WS_IDX);

  __shared__ float CUM[NS];                 // 32 KB
  __shared__ float CUM2[NS];                // 32 KB
  __shared__ float WMX[16],WMX2[16],WSM[16],WSM2[16];

  float lw[8];
  #pragma unroll
  for(int k=0;k<8;k++) lw[k]=0.0f;

  // prefetch rows for t=1
  float r_ll[8],r_h[8],r_lln[8];
  {
    const float* LLt=LL+(size_t)1*NS;
    const float* Ht=H+(size_t)1*NS;
    const float* LLNt=LLN+(size_t)1*NS;
    #pragma unroll
    for(int k=0;k<8;k++){ r_ll[k]=LLt[base+k]; r_h[k]=Ht[base+k]; r_lln[k]=LLNt[base+k]; }
  }

  for(int t=1;t<NSTEPS;t++){
    const u32* kp=KST+6*(t-1);
    const float* LLt=LL+(size_t)t*NS;   // for the LLt[lo] gather

    float s1v[8],s2v[8];
    float m1=-INFINITY,m2=-INFINITY;
    #pragma unroll
    for(int k=0;k<8;k++){
      float llv=r_ll[k], hv=r_h[k];
      s1v[k]=llv+lw[k];
      s2v[k]=s1v[k]+hv;
      m1=fmaxf(m1,s1v[k]); m2=fmaxf(m2,s2v[k]);
    }
    float wm1=wave_max(m1), wm2=wave_max(m2);
    if(lane==0){ WMX[wid]=wm1; WMX2[wid]=wm2; }
    __syncthreads();                               // sync 1
    float M1=WMX[0],M2=WMX2[0];
    #pragma unroll
    for(int w=1;w<16;w++){ M1=fmaxf(M1,WMX[w]); M2=fmaxf(M2,WMX2[w]); }

    float e1[8],e2[8]; float ts1=0.0f,ts2=0.0f;
    #pragma unroll
    for(int k=0;k<8;k++){
      e1[k]=expf(s1v[k]-M1); ts1+=e1[k];
      e2[k]=expf(s2v[k]-M2); ts2+=e2[k];
    }
    float is1=wave_incl_scan(ts1,lane);
    float is2=wave_incl_scan(ts2,lane);
    if(lane==63){ WSM[wid]=is1; WSM2[wid]=is2; }
    __syncthreads();                               // sync 2
    float T1=0.0f,T2=0.0f,woff1=0.0f,woff2=0.0f;
    #pragma unroll
    for(int w=0;w<16;w++){
      float a=WSM[w], b=WSM2[w];
      T1+=a; T2+=b;
      if(w<wid){ woff1+=a; woff2+=b; }
    }
    float excl1=woff1+(is1-ts1);
    float excl2=woff2+(is2-ts2);

    { float run=excl1;
      #pragma unroll
      for(int k=0;k<8;k++){ run+=e1[k]; CUM[base+k]=run; } }
    { float run=excl2;
      #pragma unroll
      for(int k=0;k<8;k++){ run+=e2[k]; CUM2[base+k]=run; } }
    __syncthreads();                               // sync 3

    float lwn[8];
    float u1=jax_uniform01_scalar(kp[0],kp[1]);
    #pragma unroll
    for(int k=0;k<8;k++){
      int i=base+k;
      if(i!=NS-1){
        float pos=((float)i+u1)*(1.0f/8192.0f);
        float tau=pos*T1;
        int lo=0,hi=NS;
        while(lo<hi){ int mid=(lo+hi)>>1; if(CUM[mid]<tau) lo=mid+1; else hi=mid; }
        if(lo>NS-1) lo=NS-1;
        ANC[(size_t)(t-1)*NS+i]=(u16)lo;
        lwn[k]=r_lln[k]-LLt[lo];
      }
    }
    if(tid==1023){
      float u2=jax_uniform01_scalar(kp[2],kp[3]);
      float tau=u2*T2;
      int lo=0,hi=NS;
      while(lo<hi){ int mid=(lo+hi)>>1; if(CUM2[mid]<tau) lo=mid+1; else hi=mid; }
      if(lo>NS-1) lo=NS-1;
      ANC[(size_t)(t-1)*NS+(NS-1)]=(u16)lo;
      lwn[7]=r_lln[7]-LLt[lo];
    }
    // prefetch next step's rows (hidden under remaining threads' searches)
    if(t+1<NSTEPS){
      const float* LLt2=LL+(size_t)(t+1)*NS;
      const float* Ht2=H+(size_t)(t+1)*NS;
      const float* LLNt2=LLN+(size_t)(t+1)*NS;
      #pragma unroll
      for(int k=0;k<8;k++){ r_ll[k]=LLt2[base+k]; r_h[k]=Ht2[base+k]; r_lln[k]=LLNt2[base+k]; }
    }
    #pragma unroll
    for(int k=0;k<8;k++) lw[k]=lwn[k];
    // no trailing sync: next iteration's sync 1 orders this step's CUM reads
    // before the next CUM writes (which happen only after sync 2).
  }

  // ===== final softmax over lw, draw, backward chain (r10 verbatim) =====
  {
    float m=-INFINITY;
    #pragma unroll
    for(int k=0;k<8;k++) m=fmaxf(m,lw[k]);
    float wm=wave_max(m);
    if(lane==0) WMX[wid]=wm;
    __syncthreads();
    float M=WMX[0];
    #pragma unroll
    for(int w=1;w<16;w++) M=fmaxf(M,WMX[w]);
    float e[8]; float ts=0.0f;
    #pragma unroll
    for(int k=0;k<8;k++){ e[k]=expf(lw[k]-M); ts+=e[k]; }
    float is=wave_incl_scan(ts,lane);
    if(lane==63) WSM[wid]=is;
    __syncthreads();
    float T=0.0f,woff=0.0f;
    #pragma unroll
    for(int w=0;w<16;w++){ T+=WSM[w]; if(w<wid) woff+=WSM[w]; }
    float run=woff+(is-ts);
    #pragma unroll
    for(int k=0;k<8;k++){ run+=e[k]; CUM[base+k]=run; }
    __syncthreads();
    if(tid==0){
      float u=jax_uniform01_scalar(KF[0],KF[1]);
      float tau=u*T;
      int lo=0,hi=NS;
      while(lo<hi){ int mid=(lo+hi)>>1; if(CUM[mid]<tau) lo=mid+1; else hi=mid; }
      if(lo>NS-1) lo=NS-1;
      int b=lo;
      IDX[NSTEPS-1]=b;
      for(int r=NSTEPS-2;r>=0;r--){ b=(int)ANC[(size_t)r*NS+b]; IDX[r]=b; }
    }
  }
}

// ======================= k_replay: r10 VERBATIM (frozen) ================
__global__ __launch_bounds__(256) void k_replay(
    const float* __restrict__ inp, const float* __restrict__ refst,
    const float* __restrict__ ecov, const float* __restrict__ Om,
    const float* __restrict__ ph, const float* __restrict__ coeff,
    const float* __restrict__ wsf, float* __restrict__ out)
{
  int task=blockIdx.x*blockDim.x+threadIdx.x;
  if(task>=NSTEPS) return;
  const int* IDX=(const int*)(wsf+WS_IDX);
  const u32* KST=(const u32*)(wsf+WS_KST);
  const float* CKPT=wsf+WS_CKPT;
  int t=task, p=IDX[t];
  if(p==NS-1){ for(int d=0;d<8;d++) out[t*8+d]=refst[t*8+d]; return; }
  float LEp[36]; chol8(ecov,LEp);
  int c=(t>>3)<<3;
  const float* ck=CKPT+((size_t)(t>>3)*NS+p)*8;
  float st[8];
  for(int d=0;d<8;d++) st[d]=ck[d];
  for(int s=c+1;s<=t;s++){
    float z[12];
    for(int d=0;d<8;d++) z[d]=st[d];
    for(int k=0;k<4;k++) z[8+k]=inp[s*4+k];
    float ax[8]={0,0,0,0,0,0,0,0};
    for(int j=0;j<DBc;j++){
      float dot=0.0f;
      #pragma unroll
      for(int k=0;k<12;k++) dot+=z[k]*Om[j*12+k];
      float b=cosf(dot+ph[j]);
      #pragma unroll
      for(int d=0;d<8;d++) ax[d]+=b*coeff[d*DBc+j];
    }
    const u32* kp=KST+6*(s-1);
    float eps[8];
    for(int d=0;d<8;d++) eps[d]=jax_normal_elem(kp[4],kp[5],(u32)(p*8+d));
    for(int d=0;d<8;d++){ float m=0.0f; for(int k=0;k<=d;k++) m+=eps[k]*LEp[d*(d+1)/2+k]; st[d]=ax[d]+m; }
  }
  for(int d=0;d<8;d++) out[t*8+d]=st[d];
}

// ======================= launch =======================
extern "C" void kernel_launch(void* const* d_in, const int* in_sizes, int n_in,
                              void* d_out, int out_size, void* d_ws, size_t ws_size,
                              hipStream_t stream) {
  const float* obs  =(const float*)d_in[0];
  const float* inp  =(const float*)d_in[1];
  const float* mean =(const float*)d_in[2];
  const float* icov =(const float*)d_in[3];
  const float* coeff=(const float*)d_in[4];
  const float* ecov =(const float*)d_in[5];
  const float* refst=(const float*)d_in[6];
  const float* Om   =(const float*)d_in[7];
  const float* ph   =(const float*)d_in[8];
  const float* Cm   =(const float*)d_in[9];
  const int*   seedp=(const int*)d_in[10];
  float* wsf=(float*)d_ws;
  float* out=(float*)d_out;

  hipLaunchKernelGGL(k_pre, dim3(1), dim3(256), 0, stream, seedp, wsf);
  hipLaunchKernelGGL(k_state, dim3(NS/64), dim3(64), 0, stream,
                     obs, inp, mean, icov, coeff, ecov, refst, Om, ph, Cm, wsf);
  hipLaunchKernelGGL(k_weights, dim3(1), dim3(1024), 0, stream, wsf);
  hipLaunchKernelGGL(k_replay, dim3(1), dim3(256), 0, stream,
                     inp, refst, ecov, Om, ph, coeff, wsf, out);
}